// Round 2
// baseline (207.158 us; speedup 1.0000x reference)
//
#include <hip/hip_runtime.h>
#include <hip/hip_fp16.h>
#include <math.h>

#define K_NB   32
#define C_IN   64
#define C_OUT  128
#define NPART  256   // partial-sum blocks for batchnorm stats

// ---------------------------------------------------------------------------
// K0: convert x (f32) -> fp16 copy in ws. Streaming, float4 in / 8B out.
// ---------------------------------------------------------------------------
__global__ __launch_bounds__(256) void sa_cvt(
    const float4* __restrict__ x4, uint2* __restrict__ xh, int n4)
{
    for (int i = blockIdx.x * blockDim.x + threadIdx.x; i < n4;
         i += gridDim.x * blockDim.x) {
        float4 v = x4[i];
        __half2 lo = __floats2half2_rn(v.x, v.y);
        __half2 hi = __floats2half2_rn(v.z, v.w);
        union { __half2 h; unsigned u; } a, b;
        a.h = lo; b.h = hi;
        xh[i] = make_uint2(a.u, b.u);
    }
}

// ---------------------------------------------------------------------------
// K1: fused  n_p = p[idx];  pooled = max_k [p[knn]-n_p , x[knn]];  h = pooled@W + b
// One wave per point, 4 waves/block. FP16 selects the fp16 x-copy gather path.
// h written pre-BN into the x_out region of d_out (normalized in-place by K4).
// ---------------------------------------------------------------------------
template <bool FP16>
__global__ __launch_bounds__(256) void sa_fuse(
    const float* __restrict__ p, const float* __restrict__ x,
    const __half* __restrict__ xh,
    const int* __restrict__ idx, const int* __restrict__ knn,
    const float* __restrict__ W, const float* __restrict__ bias,
    float* __restrict__ np_out, float* __restrict__ h_out)
{
    const int lane = threadIdx.x & 63;
    const int wid  = threadIdx.x >> 6;
    const int m    = blockIdx.x * 4 + wid;

    // neighbor indices: lanes 0..31 hold one each (coalesced 128B load)
    int kidx = 0;
    if (lane < K_NB) kidx = knn[m * K_NB + lane];

    // ---- feature max-pool: lane = channel, broadcast index per k ----
    float xmax = -INFINITY;
    #pragma unroll
    for (int k = 0; k < K_NB; ++k) {
        int nb = __shfl(kidx, k);                 // wave-uniform neighbor id
        float v;
        if (FP16) v = __half2float(xh[(size_t)nb * C_IN + lane]); // 128B row
        else      v = x[(size_t)nb * C_IN + lane];                // 256B row
        xmax = fmaxf(xmax, v);
    }

    // ---- xyz max-pool: lanes 0..31 load their neighbor's xyz, butterfly max ----
    float px = -INFINITY, py = -INFINITY, pz = -INFINITY;
    if (lane < K_NB) {
        const float* pp = p + (size_t)kidx * 3;
        px = pp[0]; py = pp[1]; pz = pp[2];
    }
    #pragma unroll
    for (int off = 32; off >= 1; off >>= 1) {
        px = fmaxf(px, __shfl_xor(px, off));
        py = fmaxf(py, __shfl_xor(py, off));
        pz = fmaxf(pz, __shfl_xor(pz, off));
    }

    // ---- center point (wave-uniform scalar load) ----
    const int s = idx[m];
    const float npx = p[(size_t)s*3+0];
    const float npy = p[(size_t)s*3+1];
    const float npz = p[(size_t)s*3+2];
    if (lane < 3) np_out[(size_t)m*3 + lane] = (lane == 0) ? npx : (lane == 1 ? npy : npz);

    // max_k (p[knn]-n_p) = (max_k p[knn]) - n_p  (n_p constant over k)
    const float r0 = px - npx, r1 = py - npy, r2 = pz - npz;

    // ---- Linear(67->128): each lane computes channels {lane, lane+64} ----
    float acc0 = bias[lane], acc1 = bias[64 + lane];
    acc0 = fmaf(r0, W[0*C_OUT +      lane], acc0);
    acc1 = fmaf(r0, W[0*C_OUT + 64 + lane], acc1);
    acc0 = fmaf(r1, W[1*C_OUT +      lane], acc0);
    acc1 = fmaf(r1, W[1*C_OUT + 64 + lane], acc1);
    acc0 = fmaf(r2, W[2*C_OUT +      lane], acc0);
    acc1 = fmaf(r2, W[2*C_OUT + 64 + lane], acc1);
    #pragma unroll
    for (int c = 0; c < C_IN; ++c) {
        float a = __shfl(xmax, c);                // broadcast pooled channel c
        acc0 = fmaf(a, W[(3+c)*C_OUT +      lane], acc0);  // L1-resident
        acc1 = fmaf(a, W[(3+c)*C_OUT + 64 + lane], acc1);
    }
    h_out[(size_t)m*C_OUT +      lane] = acc0;
    h_out[(size_t)m*C_OUT + 64 + lane] = acc1;
}

// ---------------------------------------------------------------------------
// K2: per-block partial column sums/sumsqs of h -> part[b][0..127]=sum,[128..255]=sumsq
// ---------------------------------------------------------------------------
__global__ __launch_bounds__(128) void sa_colsum(
    const float* __restrict__ h, float* __restrict__ part, int M)
{
    const int j = threadIdx.x;         // channel
    const int b = blockIdx.x;          // NPART blocks
    float s = 0.f, s2 = 0.f;
    for (int m = b; m < M; m += NPART) {
        float v = h[(size_t)m * C_OUT + j];
        s += v;
        s2 = fmaf(v, v, s2);
    }
    part[(size_t)b * 2 * C_OUT + j]         = s;
    part[(size_t)b * 2 * C_OUT + C_OUT + j] = s2;
}

// ---------------------------------------------------------------------------
// K3: reduce partials -> scale/shift per channel; also writes n_o
// ---------------------------------------------------------------------------
__global__ __launch_bounds__(128) void sa_finalize(
    const float* __restrict__ part, const float* __restrict__ gamma,
    const float* __restrict__ beta, float* __restrict__ ss,
    float* __restrict__ no_out, int M)
{
    const int j = threadIdx.x;
    float s = 0.f, s2 = 0.f;
    #pragma unroll 8
    for (int b = 0; b < NPART; ++b) {
        s  += part[(size_t)b * 2 * C_OUT + j];
        s2 += part[(size_t)b * 2 * C_OUT + C_OUT + j];
    }
    const float inv_m = 1.0f / (float)M;
    const float mean = s * inv_m;
    const float var  = fmaf(-mean, mean, s2 * inv_m);
    const float sc   = gamma[j] * rsqrtf(var + 1e-5f);
    ss[j]          = sc;
    ss[C_OUT + j]  = fmaf(-mean, sc, beta[j]);
    if (j == 0) no_out[0] = (float)M;    // n_o = [M]
}

// ---------------------------------------------------------------------------
// K4: in-place affine + ReLU over h (float4 vectorized)
// ---------------------------------------------------------------------------
__global__ __launch_bounds__(256) void sa_bnrelu(
    float* __restrict__ h, const float* __restrict__ ss, int M)
{
    __shared__ float sc[C_OUT], sh[C_OUT];
    if (threadIdx.x < C_OUT) {
        sc[threadIdx.x] = ss[threadIdx.x];
        sh[threadIdx.x] = ss[C_OUT + threadIdx.x];
    }
    __syncthreads();
    const size_t total4 = (size_t)M * C_OUT / 4;
    float4* h4 = (float4*)h;
    for (size_t i = (size_t)blockIdx.x * blockDim.x + threadIdx.x;
         i < total4; i += (size_t)gridDim.x * blockDim.x) {
        float4 v = h4[i];
        const int c = (int)((i * 4) & (C_OUT - 1));
        v.x = fmaxf(fmaf(v.x, sc[c+0], sh[c+0]), 0.f);
        v.y = fmaxf(fmaf(v.y, sc[c+1], sh[c+1]), 0.f);
        v.z = fmaxf(fmaf(v.z, sc[c+2], sh[c+2]), 0.f);
        v.w = fmaxf(fmaf(v.w, sc[c+3], sh[c+3]), 0.f);
        h4[i] = v;
    }
}

extern "C" void kernel_launch(void* const* d_in, const int* in_sizes, int n_in,
                              void* d_out, int out_size, void* d_ws, size_t ws_size,
                              hipStream_t stream)
{
    const float* p     = (const float*)d_in[0];
    const float* x     = (const float*)d_in[1];
    // d_in[2] = o (unused)
    const int*   idx   = (const int*)d_in[3];
    const int*   knn   = (const int*)d_in[4];
    const float* W     = (const float*)d_in[5];
    const float* bias  = (const float*)d_in[6];
    const float* gamma = (const float*)d_in[7];
    const float* beta  = (const float*)d_in[8];

    const int N = in_sizes[1] / C_IN;  // 262144
    const int M = in_sizes[3];         // 65536

    float* out    = (float*)d_out;
    float* np_out = out;                                     // [M,3]
    float* h      = out + (size_t)M * 3;                     // [M,128] pre-BN in-place
    float* no_out = out + (size_t)M * 3 + (size_t)M * C_OUT; // [1]

    const size_t xh_bytes   = (size_t)N * C_IN * sizeof(__half);      // 32 MB
    const size_t part_bytes = (size_t)NPART * 2 * C_OUT * sizeof(float);
    const bool   fp16_path  = ws_size >= xh_bytes + part_bytes + 1024;

    if (fp16_path) {
        __half* xh   = (__half*)d_ws;
        float*  part = (float*)((char*)d_ws + xh_bytes);
        float*  ss   = part + (size_t)NPART * 2 * C_OUT;

        const int n4 = N * C_IN / 4;
        sa_cvt        <<<2048, 256, 0, stream>>>((const float4*)x, (uint2*)xh, n4);
        sa_fuse<true> <<<M / 4, 256, 0, stream>>>(p, x, xh, idx, knn, W, bias, np_out, h);
        sa_colsum     <<<NPART, 128, 0, stream>>>(h, part, M);
        sa_finalize   <<<1,     128, 0, stream>>>(part, gamma, beta, ss, no_out, M);
        sa_bnrelu     <<<2048,  256, 0, stream>>>(h, ss, M);
    } else {
        float* part = (float*)d_ws;
        float* ss   = part + (size_t)NPART * 2 * C_OUT;
        sa_fuse<false><<<M / 4, 256, 0, stream>>>(p, x, nullptr, idx, knn, W, bias, np_out, h);
        sa_colsum     <<<NPART, 128, 0, stream>>>(h, part, M);
        sa_finalize   <<<1,     128, 0, stream>>>(part, gamma, beta, ss, no_out, M);
        sa_bnrelu     <<<2048,  256, 0, stream>>>(h, ss, M);
    }
}

// Round 3
// 148.703 us; speedup vs baseline: 1.3931x; 1.3931x over previous
//
#include <hip/hip_runtime.h>
#include <hip/hip_fp16.h>
#include <math.h>

#define K_NB  32
#define C_IN  64
#define C_OUT 128
#define KPAD  68     // pooled row: 64 x-ch + 3 rel-xyz + 1 zero pad (68 floats = 17 float4)

__device__ __forceinline__ float2 u2f2(unsigned u) {
    __half2 h = *reinterpret_cast<__half2*>(&u);
    return __half22float2(h);
}

// ---------------------------------------------------------------------------
// zero the BN-stat accumulators (256 floats)
// ---------------------------------------------------------------------------
__global__ __launch_bounds__(256) void sa_zero(float* __restrict__ g)
{
    g[threadIdx.x] = 0.f;
}

// ---------------------------------------------------------------------------
// x (f32) -> fp16 copy in ws
// ---------------------------------------------------------------------------
__global__ __launch_bounds__(256) void sa_cvt(
    const float4* __restrict__ x4, uint2* __restrict__ xh, int n4)
{
    for (int i = blockIdx.x * blockDim.x + threadIdx.x; i < n4;
         i += gridDim.x * blockDim.x) {
        float4 v = x4[i];
        __half2 lo = __floats2half2_rn(v.x, v.y);
        __half2 hi = __floats2half2_rn(v.z, v.w);
        union { __half2 h; unsigned u; } a, b;
        a.h = lo; b.h = hi;
        xh[i] = make_uint2(a.u, b.u);
    }
}

// ---------------------------------------------------------------------------
// pooled[m, 0..67] = [ max_k x[knn], max_k p[knn] - p[idx] , 0 ] ; n_p = p[idx]
// One wave per point. Gather: dwordx4 over fp16 rows -> 8 rows per instruction,
// 4 gather instructions total. Lane j = lane&7 owns channels 8j..8j+7.
// pooled written into the h region of d_out (cols 0..67 of each 128-col row).
// ---------------------------------------------------------------------------
__global__ __launch_bounds__(256) void sa_pool_h(
    const float* __restrict__ p, const uint4* __restrict__ xh4,
    const int* __restrict__ idx, const int* __restrict__ knn,
    float* __restrict__ np_out, float* __restrict__ pooled)
{
    const int lane = threadIdx.x & 63;
    const int m    = blockIdx.x * 4 + (threadIdx.x >> 6);

    int kidx = 0;
    if (lane < K_NB) kidx = knn[m * K_NB + lane];

    float mx[8];
    #pragma unroll
    for (int j = 0; j < 8; ++j) mx[j] = -INFINITY;

    const int sub = lane & 7;            // 16B slice within the 128B row
    #pragma unroll
    for (int i = 0; i < 4; ++i) {
        int nb = __shfl(kidx, i * 8 + (lane >> 3));   // 8 rows in flight per inst
        uint4 u = xh4[(size_t)nb * 8 + sub];
        float2 f0 = u2f2(u.x), f1 = u2f2(u.y), f2 = u2f2(u.z), f3 = u2f2(u.w);
        mx[0] = fmaxf(mx[0], f0.x); mx[1] = fmaxf(mx[1], f0.y);
        mx[2] = fmaxf(mx[2], f1.x); mx[3] = fmaxf(mx[3], f1.y);
        mx[4] = fmaxf(mx[4], f2.x); mx[5] = fmaxf(mx[5], f2.y);
        mx[6] = fmaxf(mx[6], f3.x); mx[7] = fmaxf(mx[7], f3.y);
    }
    // merge the 8 row-groups (lane bits 3,4,5)
    #pragma unroll
    for (int off = 8; off <= 32; off <<= 1)
        #pragma unroll
        for (int j = 0; j < 8; ++j)
            mx[j] = fmaxf(mx[j], __shfl_xor(mx[j], off));

    // xyz max-pool: per-lane scatter from fp32 p (3 MB, L2-resident)
    float px = -INFINITY, py = -INFINITY, pz = -INFINITY;
    if (lane < K_NB) {
        const float* pp = p + (size_t)kidx * 3;
        px = pp[0]; py = pp[1]; pz = pp[2];
    }
    #pragma unroll
    for (int off = 32; off >= 1; off >>= 1) {
        px = fmaxf(px, __shfl_xor(px, off));
        py = fmaxf(py, __shfl_xor(py, off));
        pz = fmaxf(pz, __shfl_xor(pz, off));
    }

    const int s = idx[m];
    const float npx = p[(size_t)s*3+0];
    const float npy = p[(size_t)s*3+1];
    const float npz = p[(size_t)s*3+2];
    if (lane < 3) np_out[(size_t)m*3 + lane] = (lane == 0) ? npx : (lane == 1 ? npy : npz);

    float* row = pooled + (size_t)m * C_OUT;
    if (lane < 8) {
        *(float4*)(row + lane*8)     = make_float4(mx[0], mx[1], mx[2], mx[3]);
        *(float4*)(row + lane*8 + 4) = make_float4(mx[4], mx[5], mx[6], mx[7]);
    } else if (lane == 8) {
        *(float4*)(row + C_IN) = make_float4(px - npx, py - npy, pz - npz, 0.f);
    }
}

// f32 fallback (only if ws can't hold the fp16 x copy)
__global__ __launch_bounds__(256) void sa_pool_f(
    const float* __restrict__ p, const float* __restrict__ x,
    const int* __restrict__ idx, const int* __restrict__ knn,
    float* __restrict__ np_out, float* __restrict__ pooled)
{
    const int lane = threadIdx.x & 63;
    const int m    = blockIdx.x * 4 + (threadIdx.x >> 6);
    int kidx = 0;
    if (lane < K_NB) kidx = knn[m * K_NB + lane];
    float xmax = -INFINITY;
    #pragma unroll
    for (int k = 0; k < K_NB; ++k) {
        int nb = __shfl(kidx, k);
        xmax = fmaxf(xmax, x[(size_t)nb * C_IN + lane]);
    }
    float px = -INFINITY, py = -INFINITY, pz = -INFINITY;
    if (lane < K_NB) {
        const float* pp = p + (size_t)kidx * 3;
        px = pp[0]; py = pp[1]; pz = pp[2];
    }
    #pragma unroll
    for (int off = 32; off >= 1; off >>= 1) {
        px = fmaxf(px, __shfl_xor(px, off));
        py = fmaxf(py, __shfl_xor(py, off));
        pz = fmaxf(pz, __shfl_xor(pz, off));
    }
    const int s = idx[m];
    const float npx = p[(size_t)s*3], npy = p[(size_t)s*3+1], npz = p[(size_t)s*3+2];
    if (lane < 3) np_out[(size_t)m*3 + lane] = (lane == 0) ? npx : (lane == 1 ? npy : npz);
    float* row = pooled + (size_t)m * C_OUT;
    row[lane] = xmax;
    if (lane == 0) *(float4*)(row + C_IN) = make_float4(px-npx, py-npy, pz-npz, 0.f);
}

// ---------------------------------------------------------------------------
// h[m,:] = pooled[m,:] @ Wp + b  (Wp = permuted W, pooled col j<64 -> W row 3+j,
// cols 64..66 -> W rows 0..2).  64 rows x 128 cols per block, 32 outputs/thread.
// Fused BN partial stats -> atomicAdd into gsum[0..127]=sum, [128..255]=sumsq.
// pooled aliases h rows (cols 0..67) — all global reads happen before barrier.
// ---------------------------------------------------------------------------
__global__ __launch_bounds__(256) void sa_gemm(
    const float* __restrict__ W, const float* __restrict__ bias,
    float* __restrict__ h, float* __restrict__ gsum)
{
    __shared__ float Wl[KPAD * C_OUT];        // 34.8 KB
    __shared__ float Pl[64 * KPAD];           // 17.4 KB
    __shared__ float reds[8][C_OUT];          // 4 KB
    __shared__ float redq[8][C_OUT];          // 4 KB
    const int t  = threadIdx.x;
    const int m0 = blockIdx.x * 64;

    for (int v = t; v < KPAD * C_OUT; v += 256) {
        const int j = v >> 7, col = v & 127;
        float w = 0.f;
        if (j < C_IN)          w = W[(size_t)(3 + j) * C_OUT + col];
        else if (j < C_IN + 3) w = W[(size_t)(j - C_IN) * C_OUT + col];
        Wl[v] = w;
    }
    const float4* h4 = (const float4*)(h + (size_t)m0 * C_OUT);
    for (int v = t; v < 64 * 17; v += 256) {
        const int r = v / 17, q = v - r * 17;
        *(float4*)&Pl[r * KPAD + q * 4] = h4[r * 32 + q];
    }
    __syncthreads();

    const int c0 = (t & 31) * 4;
    const int r0 = (t >> 5) * 8;
    const float4 bv = *(const float4*)&bias[c0];
    float acc[8][4];
    #pragma unroll
    for (int i = 0; i < 8; ++i) {
        acc[i][0] = bv.x; acc[i][1] = bv.y; acc[i][2] = bv.z; acc[i][3] = bv.w;
    }
    for (int c = 0; c < 67; ++c) {            // col 67 is the zero pad
        const float4 w4 = *(const float4*)&Wl[c * C_OUT + c0];
        #pragma unroll
        for (int i = 0; i < 8; ++i) {
            const float a = Pl[(r0 + i) * KPAD + c];
            acc[i][0] = fmaf(a, w4.x, acc[i][0]);
            acc[i][1] = fmaf(a, w4.y, acc[i][1]);
            acc[i][2] = fmaf(a, w4.z, acc[i][2]);
            acc[i][3] = fmaf(a, w4.w, acc[i][3]);
        }
    }
    float s[4] = {0,0,0,0}, q[4] = {0,0,0,0};
    #pragma unroll
    for (int i = 0; i < 8; ++i) {
        *(float4*)&h[(size_t)(m0 + r0 + i) * C_OUT + c0] =
            make_float4(acc[i][0], acc[i][1], acc[i][2], acc[i][3]);
        #pragma unroll
        for (int j = 0; j < 4; ++j) {
            s[j] += acc[i][j];
            q[j]  = fmaf(acc[i][j], acc[i][j], q[j]);
        }
    }
    #pragma unroll
    for (int j = 0; j < 4; ++j) {
        reds[t >> 5][c0 + j] = s[j];
        redq[t >> 5][c0 + j] = q[j];
    }
    __syncthreads();
    if (t < C_OUT) {
        float ss = 0.f, qq = 0.f;
        #pragma unroll
        for (int i = 0; i < 8; ++i) { ss += reds[i][t]; qq += redq[i][t]; }
        atomicAdd(&gsum[t],         ss);
        atomicAdd(&gsum[C_OUT + t], qq);
    }
}

// ---------------------------------------------------------------------------
// gsum -> per-channel scale/shift; writes n_o
// ---------------------------------------------------------------------------
__global__ __launch_bounds__(128) void sa_finalize(
    const float* __restrict__ gsum, const float* __restrict__ gamma,
    const float* __restrict__ beta, float* __restrict__ ss,
    float* __restrict__ no_out, int M)
{
    const int j = threadIdx.x;
    const float inv_m = 1.0f / (float)M;
    const float mean = gsum[j] * inv_m;
    const float var  = fmaf(-mean, mean, gsum[C_OUT + j] * inv_m);
    const float sc   = gamma[j] * rsqrtf(var + 1e-5f);
    ss[j]         = sc;
    ss[C_OUT + j] = fmaf(-mean, sc, beta[j]);
    if (j == 0) no_out[0] = (float)M;
}

// ---------------------------------------------------------------------------
// in-place affine + ReLU over h (float4)
// ---------------------------------------------------------------------------
__global__ __launch_bounds__(256) void sa_bnrelu(
    float* __restrict__ h, const float* __restrict__ ss, int M)
{
    __shared__ float sc[C_OUT], sh[C_OUT];
    if (threadIdx.x < C_OUT) {
        sc[threadIdx.x] = ss[threadIdx.x];
        sh[threadIdx.x] = ss[C_OUT + threadIdx.x];
    }
    __syncthreads();
    const size_t total4 = (size_t)M * C_OUT / 4;
    float4* h4 = (float4*)h;
    for (size_t i = (size_t)blockIdx.x * blockDim.x + threadIdx.x;
         i < total4; i += (size_t)gridDim.x * blockDim.x) {
        float4 v = h4[i];
        const int c = (int)((i * 4) & (C_OUT - 1));
        v.x = fmaxf(fmaf(v.x, sc[c+0], sh[c+0]), 0.f);
        v.y = fmaxf(fmaf(v.y, sc[c+1], sh[c+1]), 0.f);
        v.z = fmaxf(fmaf(v.z, sc[c+2], sh[c+2]), 0.f);
        v.w = fmaxf(fmaf(v.w, sc[c+3], sh[c+3]), 0.f);
        h4[i] = v;
    }
}

extern "C" void kernel_launch(void* const* d_in, const int* in_sizes, int n_in,
                              void* d_out, int out_size, void* d_ws, size_t ws_size,
                              hipStream_t stream)
{
    const float* p     = (const float*)d_in[0];
    const float* x     = (const float*)d_in[1];
    // d_in[2] = o (unused)
    const int*   idx   = (const int*)d_in[3];
    const int*   knn   = (const int*)d_in[4];
    const float* W     = (const float*)d_in[5];
    const float* bias  = (const float*)d_in[6];
    const float* gamma = (const float*)d_in[7];
    const float* beta  = (const float*)d_in[8];

    const int N = in_sizes[1] / C_IN;  // 262144
    const int M = in_sizes[3];         // 65536

    float* out    = (float*)d_out;
    float* np_out = out;                                     // [M,3]
    float* h      = out + (size_t)M * 3;                     // [M,128]
    float* no_out = out + (size_t)M * 3 + (size_t)M * C_OUT; // [1]

    const size_t xh_bytes  = (size_t)N * C_IN * sizeof(__half);   // 32 MB
    const bool   fp16_path = ws_size >= xh_bytes + 2048;

    float* gsum = fp16_path ? (float*)((char*)d_ws + xh_bytes) : (float*)d_ws;
    float* ss   = gsum + 2 * C_OUT;

    sa_zero<<<1, 256, 0, stream>>>(gsum);
    if (fp16_path) {
        __half* xh = (__half*)d_ws;
        const int n4 = N * C_IN / 4;
        sa_cvt   <<<2048, 256, 0, stream>>>((const float4*)x, (uint2*)xh, n4);
        sa_pool_h<<<M / 4, 256, 0, stream>>>(p, (const uint4*)xh, idx, knn, np_out, h);
    } else {
        sa_pool_f<<<M / 4, 256, 0, stream>>>(p, x, idx, knn, np_out, h);
    }
    sa_gemm    <<<M / 64, 256, 0, stream>>>(W, bias, h, gsum);
    sa_finalize<<<1,      128, 0, stream>>>(gsum, gamma, beta, ss, no_out, M);
    sa_bnrelu  <<<2048,   256, 0, stream>>>(h, ss, M);
}

// Round 4
// 146.539 us; speedup vs baseline: 1.4137x; 1.0148x over previous
//
#include <hip/hip_runtime.h>
#include <hip/hip_fp16.h>
#include <math.h>

#define K_NB  32
#define C_IN  64
#define C_OUT 128
#define KPAD  68     // pooled row: 64 x-ch + 3 rel-xyz + 1 zero pad

__device__ __forceinline__ float2 u2f2(unsigned u) {
    __half2 h = *reinterpret_cast<__half2*>(&u);
    return __half22float2(h);
}

// ---------------------------------------------------------------------------
// zero the BN-stat accumulators (256 floats)
// ---------------------------------------------------------------------------
__global__ __launch_bounds__(256) void sa_zero(float* __restrict__ g)
{
    g[threadIdx.x] = 0.f;
}

// ---------------------------------------------------------------------------
// x (f32) -> fp16 copy in ws
// ---------------------------------------------------------------------------
__global__ __launch_bounds__(256) void sa_cvt(
    const float4* __restrict__ x4, uint2* __restrict__ xh, int n4)
{
    for (int i = blockIdx.x * blockDim.x + threadIdx.x; i < n4;
         i += gridDim.x * blockDim.x) {
        float4 v = x4[i];
        __half2 lo = __floats2half2_rn(v.x, v.y);
        __half2 hi = __floats2half2_rn(v.z, v.w);
        union { __half2 h; unsigned u; } a, b;
        a.h = lo; b.h = hi;
        xh[i] = make_uint2(a.u, b.u);
    }
}

// ---------------------------------------------------------------------------
// pooled[m, 0..67] = [ max_k x[knn], max_k p[knn] - p[idx], 0 ] ; n_p = p[idx]
// One wave per point; gather via dwordx4 over fp16 rows (8 rows / instruction).
// pooled written into the h region of d_out (cols 0..67 of each 128-col row).
// ---------------------------------------------------------------------------
__global__ __launch_bounds__(256) void sa_pool_h(
    const float* __restrict__ p, const uint4* __restrict__ xh4,
    const int* __restrict__ idx, const int* __restrict__ knn,
    float* __restrict__ np_out, float* __restrict__ pooled)
{
    const int lane = threadIdx.x & 63;
    const int m    = blockIdx.x * 4 + (threadIdx.x >> 6);

    int kidx = 0;
    if (lane < K_NB) kidx = knn[m * K_NB + lane];

    float mx[8];
    #pragma unroll
    for (int j = 0; j < 8; ++j) mx[j] = -INFINITY;

    const int sub = lane & 7;            // 16B slice within the 128B row
    #pragma unroll
    for (int i = 0; i < 4; ++i) {
        int nb = __shfl(kidx, i * 8 + (lane >> 3));   // 8 rows in flight per inst
        uint4 u = xh4[(size_t)nb * 8 + sub];
        float2 f0 = u2f2(u.x), f1 = u2f2(u.y), f2 = u2f2(u.z), f3 = u2f2(u.w);
        mx[0] = fmaxf(mx[0], f0.x); mx[1] = fmaxf(mx[1], f0.y);
        mx[2] = fmaxf(mx[2], f1.x); mx[3] = fmaxf(mx[3], f1.y);
        mx[4] = fmaxf(mx[4], f2.x); mx[5] = fmaxf(mx[5], f2.y);
        mx[6] = fmaxf(mx[6], f3.x); mx[7] = fmaxf(mx[7], f3.y);
    }
    // merge the 8 row-groups (lane bits 3,4,5)
    #pragma unroll
    for (int off = 8; off <= 32; off <<= 1)
        #pragma unroll
        for (int j = 0; j < 8; ++j)
            mx[j] = fmaxf(mx[j], __shfl_xor(mx[j], off));

    // xyz max-pool (fp32 p, L2-resident)
    float px = -INFINITY, py = -INFINITY, pz = -INFINITY;
    if (lane < K_NB) {
        const float* pp = p + (size_t)kidx * 3;
        px = pp[0]; py = pp[1]; pz = pp[2];
    }
    #pragma unroll
    for (int off = 32; off >= 1; off >>= 1) {
        px = fmaxf(px, __shfl_xor(px, off));
        py = fmaxf(py, __shfl_xor(py, off));
        pz = fmaxf(pz, __shfl_xor(pz, off));
    }

    const int s = idx[m];
    const float npx = p[(size_t)s*3+0];
    const float npy = p[(size_t)s*3+1];
    const float npz = p[(size_t)s*3+2];
    if (lane < 3) np_out[(size_t)m*3 + lane] = (lane == 0) ? npx : (lane == 1 ? npy : npz);

    float* row = pooled + (size_t)m * C_OUT;
    if (lane < 8) {
        *(float4*)(row + lane*8)     = make_float4(mx[0], mx[1], mx[2], mx[3]);
        *(float4*)(row + lane*8 + 4) = make_float4(mx[4], mx[5], mx[6], mx[7]);
    } else if (lane == 8) {
        *(float4*)(row + C_IN) = make_float4(px - npx, py - npy, pz - npz, 0.f);
    }
}

// f32 fallback (only if ws can't hold the fp16 x copy)
__global__ __launch_bounds__(256) void sa_pool_f(
    const float* __restrict__ p, const float* __restrict__ x,
    const int* __restrict__ idx, const int* __restrict__ knn,
    float* __restrict__ np_out, float* __restrict__ pooled)
{
    const int lane = threadIdx.x & 63;
    const int m    = blockIdx.x * 4 + (threadIdx.x >> 6);
    int kidx = 0;
    if (lane < K_NB) kidx = knn[m * K_NB + lane];
    float xmax = -INFINITY;
    #pragma unroll
    for (int k = 0; k < K_NB; ++k) {
        int nb = __shfl(kidx, k);
        xmax = fmaxf(xmax, x[(size_t)nb * C_IN + lane]);
    }
    float px = -INFINITY, py = -INFINITY, pz = -INFINITY;
    if (lane < K_NB) {
        const float* pp = p + (size_t)kidx * 3;
        px = pp[0]; py = pp[1]; pz = pp[2];
    }
    #pragma unroll
    for (int off = 32; off >= 1; off >>= 1) {
        px = fmaxf(px, __shfl_xor(px, off));
        py = fmaxf(py, __shfl_xor(py, off));
        pz = fmaxf(pz, __shfl_xor(pz, off));
    }
    const int s = idx[m];
    const float npx = p[(size_t)s*3], npy = p[(size_t)s*3+1], npz = p[(size_t)s*3+2];
    if (lane < 3) np_out[(size_t)m*3 + lane] = (lane == 0) ? npx : (lane == 1 ? npy : npz);
    float* row = pooled + (size_t)m * C_OUT;
    row[lane] = xmax;
    if (lane == 0) *(float4*)(row + C_IN) = make_float4(px-npx, py-npy, pz-npz, 0.f);
}

// ---------------------------------------------------------------------------
// h[m,:] = pooled[m,:] @ Wp + b  with fused BN partial stats.
// 64 rows x 128 cols per block, 256 threads, 8 rows x 4 cols per thread.
// Pooled tile staged TRANSPOSED (PlT[c][row]) so per-K-step activation reads
// are 2x ds_read_b128 instead of 8x ds_read_b32. LDS 52.1 KB -> 3 blocks/CU.
// PlT space is reused (after barrier) for the stats reduction.
// ---------------------------------------------------------------------------
__global__ __launch_bounds__(256) void sa_gemm(
    const float* __restrict__ W, const float* __restrict__ bias,
    float* __restrict__ h, float* __restrict__ gsum)
{
    __shared__ float Wl[KPAD * C_OUT];   // 34816 B
    __shared__ float PlT[KPAD][KPAD];    // 18496 B (row len 68 keeps 16B alignment)
    const int t  = threadIdx.x;
    const int m0 = blockIdx.x * 64;

    // stage W permuted: pooled col j<64 -> W row 3+j; cols 64..66 -> rows 0..2; 67 -> 0
    for (int v = t; v < KPAD * C_OUT; v += 256) {
        const int j = v >> 7, col = v & 127;
        float w = 0.f;
        if (j < C_IN)          w = W[(size_t)(3 + j) * C_OUT + col];
        else if (j < C_IN + 3) w = W[(size_t)(j - C_IN) * C_OUT + col];
        Wl[v] = w;
    }
    // stage pooled transposed
    const float4* h4 = (const float4*)(h + (size_t)m0 * C_OUT);
    for (int v = t; v < 64 * 17; v += 256) {
        const int r = v / 17, q = v - r * 17;
        float4 f = h4[r * 32 + q];
        PlT[4*q+0][r] = f.x;
        PlT[4*q+1][r] = f.y;
        PlT[4*q+2][r] = f.z;
        PlT[4*q+3][r] = f.w;
    }
    __syncthreads();

    const int c0 = (t & 31) * 4;
    const int r0 = (t >> 5) * 8;
    const float4 bv = *(const float4*)&bias[c0];
    float acc[8][4];
    #pragma unroll
    for (int i = 0; i < 8; ++i) {
        acc[i][0] = bv.x; acc[i][1] = bv.y; acc[i][2] = bv.z; acc[i][3] = bv.w;
    }
    for (int c = 0; c < 67; ++c) {
        const float4 w4 = *(const float4*)&Wl[c * C_OUT + c0];
        const float4 a0 = *(const float4*)&PlT[c][r0];
        const float4 a1 = *(const float4*)&PlT[c][r0 + 4];
        const float a[8] = {a0.x, a0.y, a0.z, a0.w, a1.x, a1.y, a1.z, a1.w};
        #pragma unroll
        for (int i = 0; i < 8; ++i) {
            acc[i][0] = fmaf(a[i], w4.x, acc[i][0]);
            acc[i][1] = fmaf(a[i], w4.y, acc[i][1]);
            acc[i][2] = fmaf(a[i], w4.z, acc[i][2]);
            acc[i][3] = fmaf(a[i], w4.w, acc[i][3]);
        }
    }

    float s[4] = {0,0,0,0}, q[4] = {0,0,0,0};
    #pragma unroll
    for (int i = 0; i < 8; ++i) {
        *(float4*)&h[(size_t)(m0 + r0 + i) * C_OUT + c0] =
            make_float4(acc[i][0], acc[i][1], acc[i][2], acc[i][3]);
        #pragma unroll
        for (int j = 0; j < 4; ++j) {
            s[j] += acc[i][j];
            q[j]  = fmaf(acc[i][j], acc[i][j], q[j]);
        }
    }

    __syncthreads();                       // PlT reads done; reuse for reduction
    float* reds = &PlT[0][0];              // 8*128 floats
    float* redq = reds + 8 * C_OUT;        // 8*128 floats (fits in 68*68)
    #pragma unroll
    for (int j = 0; j < 4; ++j) {
        reds[(t >> 5) * C_OUT + c0 + j] = s[j];
        redq[(t >> 5) * C_OUT + c0 + j] = q[j];
    }
    __syncthreads();
    if (t < C_OUT) {
        float ss = 0.f, qq = 0.f;
        #pragma unroll
        for (int i = 0; i < 8; ++i) { ss += reds[i * C_OUT + t]; qq += redq[i * C_OUT + t]; }
        atomicAdd(&gsum[t],         ss);
        atomicAdd(&gsum[C_OUT + t], qq);
    }
}

// ---------------------------------------------------------------------------
// gsum -> per-channel scale/shift; writes n_o
// ---------------------------------------------------------------------------
__global__ __launch_bounds__(128) void sa_finalize(
    const float* __restrict__ gsum, const float* __restrict__ gamma,
    const float* __restrict__ beta, float* __restrict__ ss,
    float* __restrict__ no_out, int M)
{
    const int j = threadIdx.x;
    const float inv_m = 1.0f / (float)M;
    const float mean = gsum[j] * inv_m;
    const float var  = fmaf(-mean, mean, gsum[C_OUT + j] * inv_m);
    const float sc   = gamma[j] * rsqrtf(var + 1e-5f);
    ss[j]         = sc;
    ss[C_OUT + j] = fmaf(-mean, sc, beta[j]);
    if (j == 0) no_out[0] = (float)M;
}

// ---------------------------------------------------------------------------
// in-place affine + ReLU over h (float4)
// ---------------------------------------------------------------------------
__global__ __launch_bounds__(256) void sa_bnrelu(
    float* __restrict__ h, const float* __restrict__ ss, int M)
{
    __shared__ float sc[C_OUT], sh[C_OUT];
    if (threadIdx.x < C_OUT) {
        sc[threadIdx.x] = ss[threadIdx.x];
        sh[threadIdx.x] = ss[C_OUT + threadIdx.x];
    }
    __syncthreads();
    const size_t total4 = (size_t)M * C_OUT / 4;
    float4* h4 = (float4*)h;
    for (size_t i = (size_t)blockIdx.x * blockDim.x + threadIdx.x;
         i < total4; i += (size_t)gridDim.x * blockDim.x) {
        float4 v = h4[i];
        const int c = (int)((i * 4) & (C_OUT - 1));
        v.x = fmaxf(fmaf(v.x, sc[c+0], sh[c+0]), 0.f);
        v.y = fmaxf(fmaf(v.y, sc[c+1], sh[c+1]), 0.f);
        v.z = fmaxf(fmaf(v.z, sc[c+2], sh[c+2]), 0.f);
        v.w = fmaxf(fmaf(v.w, sc[c+3], sh[c+3]), 0.f);
        h4[i] = v;
    }
}

extern "C" void kernel_launch(void* const* d_in, const int* in_sizes, int n_in,
                              void* d_out, int out_size, void* d_ws, size_t ws_size,
                              hipStream_t stream)
{
    const float* p     = (const float*)d_in[0];
    const float* x     = (const float*)d_in[1];
    // d_in[2] = o (unused)
    const int*   idx   = (const int*)d_in[3];
    const int*   knn   = (const int*)d_in[4];
    const float* W     = (const float*)d_in[5];
    const float* bias  = (const float*)d_in[6];
    const float* gamma = (const float*)d_in[7];
    const float* beta  = (const float*)d_in[8];

    const int N = in_sizes[1] / C_IN;  // 262144
    const int M = in_sizes[3];         // 65536

    float* out    = (float*)d_out;
    float* np_out = out;                                     // [M,3]
    float* h      = out + (size_t)M * 3;                     // [M,128]
    float* no_out = out + (size_t)M * 3 + (size_t)M * C_OUT; // [1]

    const size_t xh_bytes  = (size_t)N * C_IN * sizeof(__half);   // 32 MB
    const bool   fp16_path = ws_size >= xh_bytes + 2048;

    float* gsum = fp16_path ? (float*)((char*)d_ws + xh_bytes) : (float*)d_ws;
    float* ss   = gsum + 2 * C_OUT;

    sa_zero<<<1, 256, 0, stream>>>(gsum);
    if (fp16_path) {
        __half* xh = (__half*)d_ws;
        const int n4 = N * C_IN / 4;
        sa_cvt   <<<2048, 256, 0, stream>>>((const float4*)x, (uint2*)xh, n4);
        sa_pool_h<<<M / 4, 256, 0, stream>>>(p, (const uint4*)xh, idx, knn, np_out, h);
    } else {
        sa_pool_f<<<M / 4, 256, 0, stream>>>(p, x, idx, knn, np_out, h);
    }
    sa_gemm    <<<M / 64, 256, 0, stream>>>(W, bias, h, gsum);
    sa_finalize<<<1,      128, 0, stream>>>(gsum, gamma, beta, ss, no_out, M);
    sa_bnrelu  <<<2048,   256, 0, stream>>>(h, ss, M);
}